// Round 2
// baseline (9.918 us; speedup 1.0000x reference)
//
#include <hip/hip_runtime.h>
#include <stdint.h>

#define NN 50000
#define NE 800000

typedef float f32x4 __attribute__((ext_vector_type(4)));
typedef short s16x8 __attribute__((ext_vector_type(8)));

__device__ __forceinline__ float bf2f(unsigned short u) {
    union { unsigned int i; float f; } v; v.i = ((unsigned int)u) << 16; return v.f;
}
__device__ __forceinline__ unsigned short f2bf(float x) {
    union { float f; unsigned int i; } v; v.f = x;
    unsigned int r = v.i + 0x7FFFu + ((v.i >> 16) & 1u);
    return (unsigned short)(r >> 16);
}

// ---------------- graph preprocessing ----------------

__global__ void k_deg(const int* __restrict__ src, const int* __restrict__ dst,
                      int* __restrict__ dego, int* __restrict__ degi) {
    int e = blockIdx.x * 256 + threadIdx.x;
    if (e < NE) {
        atomicAdd(&dego[src[e]], 1);
        atomicAdd(&degi[dst[e]], 1);
    }
}

__global__ void k_norm(const int* __restrict__ dego, const int* __restrict__ degi,
                       float* __restrict__ ns, float* __restrict__ nd) {
    int i = blockIdx.x * 256 + threadIdx.x;
    if (i < NN) {
        ns[i] = dego[i] > 0 ? rsqrtf((float)dego[i]) : 0.f;
        nd[i] = degi[i] > 0 ? rsqrtf((float)degi[i]) : 0.f;
    }
}

__global__ void k_scan(const int* __restrict__ deg, int* __restrict__ row_ptr,
                       int* __restrict__ cursor) {
    __shared__ int tmp[1024];
    __shared__ int carry_s;
    if (threadIdx.x == 0) carry_s = 0;
    __syncthreads();
    for (int base = 0; base < NN; base += 1024) {
        int i = base + (int)threadIdx.x;
        int v = (i < NN) ? deg[i] : 0;
        int c = carry_s;
        tmp[threadIdx.x] = v;
        __syncthreads();
        int sum = v;
        for (int off = 1; off < 1024; off <<= 1) {
            int t = (threadIdx.x >= (unsigned)off) ? tmp[threadIdx.x - off] : 0;
            __syncthreads();
            sum += t;
            tmp[threadIdx.x] = sum;
            __syncthreads();
        }
        if (i < NN) { int ex = c + sum - v; row_ptr[i] = ex; cursor[i] = ex; }
        __syncthreads();
        if (threadIdx.x == 0) carry_s = c + tmp[1023];
        __syncthreads();
    }
    if (threadIdx.x == 0) row_ptr[NN] = carry_s;
}

__global__ void k_fill(const int* __restrict__ src, const int* __restrict__ dst,
                       int* __restrict__ cursor, int* __restrict__ col_src) {
    int e = blockIdx.x * 256 + threadIdx.x;
    if (e < NE) {
        int slot = atomicAdd(&cursor[dst[e]], 1);
        col_src[slot] = src[e];
    }
}

// W [K,Ncols] fp32 row-major -> Wt hi/lo [Ncols,K] bf16 (B^T layout)
__global__ void k_wsplit(const float* __restrict__ W, unsigned short* __restrict__ hi,
                         unsigned short* __restrict__ lo, int K, int Ncols) {
    int idx = blockIdx.x * 256 + threadIdx.x;
    if (idx < K * Ncols) {
        int n = idx / K, k = idx - n * K;
        float w = W[(size_t)k * Ncols + n];
        unsigned short h = f2bf(w);
        hi[idx] = h;
        lo[idx] = f2bf(w - bf2f(h));
    }
}

// ---------------- GCN propagate: y[d] = nd[d] * sum_{e:dst=d} ns[s] * x[s] ----------------
// One wave per node; lane owns 4 consecutive cols (coalesced 1KB row reads).

__global__ void k_prop(const float* __restrict__ x, int ldx,
                       const int* __restrict__ row_ptr, const int* __restrict__ col_src,
                       const float* __restrict__ ns, const float* __restrict__ ndv,
                       float* __restrict__ y) {
    int w = (int)((blockIdx.x * 256 + threadIdx.x) >> 6);
    if (w >= NN) return;
    int lane = threadIdx.x & 63;
    int c = lane * 4;
    float a0 = 0, a1 = 0, a2 = 0, a3 = 0;
    int e0 = row_ptr[w], e1 = row_ptr[w + 1];
    for (int p = e0; p < e1; ++p) {
        int s = col_src[p];
        float wgt = ns[s];
        const float4 xv = *(const float4*)(x + (size_t)s * ldx + c);
        a0 += wgt * xv.x; a1 += wgt * xv.y; a2 += wgt * xv.z; a3 += wgt * xv.w;
    }
    float sc = ndv[w];
    float4 o; o.x = a0 * sc; o.y = a1 * sc; o.z = a2 * sc; o.w = a3 * sc;
    *(float4*)(y + (size_t)w * 256 + c) = o;
}

// ---------------- edge attention ----------------
// QKV [NN,768] fp32: cols 0-255 Q, 256-511 K, 512-767 V. One wave per dst node.
// 16-lane group g handles head g; lane covers 4 dims of that head.

__global__ void k_attn(const float* __restrict__ QKV,
                       const int* __restrict__ row_ptr, const int* __restrict__ col_src,
                       float* __restrict__ xo) {
    int w = (int)((blockIdx.x * 256 + threadIdx.x) >> 6);
    if (w >= NN) return;
    int lane = threadIdx.x & 63;
    int c = lane * 4;
    const float4 q = *(const float4*)(QKV + (size_t)w * 768 + c);
    float v0 = 0, v1 = 0, v2 = 0, v3 = 0, z = 0;
    int e0 = row_ptr[w], e1 = row_ptr[w + 1];
    for (int p = e0; p < e1; ++p) {
        int s = col_src[p];
        const float4 kk = *(const float4*)(QKV + (size_t)s * 768 + 256 + c);
        float t = q.x * kk.x + q.y * kk.y + q.z * kk.z + q.w * kk.w;
        t += __shfl_xor(t, 1);
        t += __shfl_xor(t, 2);
        t += __shfl_xor(t, 4);
        t += __shfl_xor(t, 8);
        float scv = __expf(fminf(fmaxf(t * 0.125f, -10.f), 10.f));
        const float4 vv = *(const float4*)(QKV + (size_t)s * 768 + 512 + c);
        v0 += scv * vv.x; v1 += scv * vv.y; v2 += scv * vv.z; v3 += scv * vv.w;
        z += scv;
    }
    float inv = 1.f / (z + 1e-6f);
    float4 o; o.x = v0 * inv; o.y = v1 * inv; o.z = v2 * inv; o.w = v3 * inv;
    *(float4*)(xo + (size_t)w * 768 + c) = o;
}

// ---------------- split-bf16 GEMM: C = relu(A @ W + b) ----------------
// A: fp32 [M,K] (lda), split to hi/lo bf16 in registers during LDS staging.
// B: hi/lo bf16 B^T [Ncols,K]. 3-term MFMA (hh + hl + lh) ~ fp32 accuracy.
// 128x128 tile, BK=32, 4 waves (2x2 of 64x64), mfma_f32_16x16x32_bf16.

__global__ __launch_bounds__(256) void k_gemm(
    const float* __restrict__ A, int lda,
    const unsigned short* __restrict__ Bhi, const unsigned short* __restrict__ Blo,
    const float* __restrict__ bias,
    float* __restrict__ C, int ldc, int coff, int M, int K) {
    __shared__ unsigned short sA[2][128][40];
    __shared__ unsigned short sB[2][128][40];
    const int tid = threadIdx.x;
    const int lane = tid & 63;
    const int wid = tid >> 6;
    const int wm = wid & 1, wn = wid >> 1;
    const int fr = lane & 15, kg = lane >> 4;
    const int brow = blockIdx.x * 128;
    const int bcol = blockIdx.y * 128;
    f32x4 acc[4][4] = {};

    for (int k0 = 0; k0 < K; k0 += 32) {
#pragma unroll
        for (int rep = 0; rep < 2; ++rep) {
            int s = tid + rep * 256;
            int row = s >> 2, ks = (s & 3) * 8;
            int gr = brow + row;
            float4 f0 = make_float4(0, 0, 0, 0), f1 = make_float4(0, 0, 0, 0);
            if (gr < M) {
                const float4* ap = (const float4*)(A + (size_t)gr * lda + k0 + ks);
                f0 = ap[0];
                f1 = ap[1];
            }
            ushort4 h0, h1v, l0, l1v;
            h0.x = f2bf(f0.x); l0.x = f2bf(f0.x - bf2f(h0.x));
            h0.y = f2bf(f0.y); l0.y = f2bf(f0.y - bf2f(h0.y));
            h0.z = f2bf(f0.z); l0.z = f2bf(f0.z - bf2f(h0.z));
            h0.w = f2bf(f0.w); l0.w = f2bf(f0.w - bf2f(h0.w));
            h1v.x = f2bf(f1.x); l1v.x = f2bf(f1.x - bf2f(h1v.x));
            h1v.y = f2bf(f1.y); l1v.y = f2bf(f1.y - bf2f(h1v.y));
            h1v.z = f2bf(f1.z); l1v.z = f2bf(f1.z - bf2f(h1v.z));
            h1v.w = f2bf(f1.w); l1v.w = f2bf(f1.w - bf2f(h1v.w));
            *(ushort4*)&sA[0][row][ks] = h0;
            *(ushort4*)&sA[0][row][ks + 4] = h1v;
            *(ushort4*)&sA[1][row][ks] = l0;
            *(ushort4*)&sA[1][row][ks + 4] = l1v;
            size_t bbase = (size_t)(bcol + row) * K + k0 + ks;
            *(uint4*)&sB[0][row][ks] = *(const uint4*)(Bhi + bbase);
            *(uint4*)&sB[1][row][ks] = *(const uint4*)(Blo + bbase);
        }
        __syncthreads();
        s16x8 ah[4], al[4], bh[4], bl[4];
#pragma unroll
        for (int f = 0; f < 4; ++f) {
            ah[f] = *(const s16x8*)&sA[0][wm * 64 + f * 16 + fr][kg * 8];
            al[f] = *(const s16x8*)&sA[1][wm * 64 + f * 16 + fr][kg * 8];
            bh[f] = *(const s16x8*)&sB[0][wn * 64 + f * 16 + fr][kg * 8];
            bl[f] = *(const s16x8*)&sB[1][wn * 64 + f * 16 + fr][kg * 8];
        }
#pragma unroll
        for (int i = 0; i < 4; ++i)
#pragma unroll
            for (int j = 0; j < 4; ++j) {
                acc[i][j] = __builtin_amdgcn_mfma_f32_16x16x32_bf16(ah[i], bh[j], acc[i][j], 0, 0, 0);
                acc[i][j] = __builtin_amdgcn_mfma_f32_16x16x32_bf16(ah[i], bl[j], acc[i][j], 0, 0, 0);
                acc[i][j] = __builtin_amdgcn_mfma_f32_16x16x32_bf16(al[i], bh[j], acc[i][j], 0, 0, 0);
            }
        __syncthreads();
    }

#pragma unroll
    for (int i = 0; i < 4; ++i) {
#pragma unroll
        for (int j = 0; j < 4; ++j) {
            int colL = bcol + wn * 64 + j * 16 + fr;
            float bb = bias[colL];
#pragma unroll
            for (int r = 0; r < 4; ++r) {
                int row = brow + wm * 64 + i * 16 + kg * 4 + r;
                if (row < M) {
                    C[(size_t)row * ldc + coff + colL] = fmaxf(acc[i][j][r] + bb, 0.f);
                }
            }
        }
    }
}

// ---------------- final row-dot + sigmoid ----------------

__global__ void k_final(const float* __restrict__ h2, const float* __restrict__ W3,
                        const float* __restrict__ b3, float* __restrict__ out) {
    int w = (int)((blockIdx.x * 256 + threadIdx.x) >> 6);
    if (w >= NN) return;
    int lane = threadIdx.x & 63;
    float4 h = *(const float4*)(h2 + (size_t)w * 256 + lane * 4);
    float4 ww = *(const float4*)(W3 + lane * 4);
    float p = h.x * ww.x + h.y * ww.y + h.z * ww.z + h.w * ww.w;
    p += __shfl_xor(p, 1);
    p += __shfl_xor(p, 2);
    p += __shfl_xor(p, 4);
    p += __shfl_xor(p, 8);
    p += __shfl_xor(p, 16);
    p += __shfl_xor(p, 32);
    if (lane == 0) out[w] = 1.f / (1.f + __expf(-(p + b3[0])));
}

// sentinel: written iff ws_size is too small (diagnosable absmax ~= 0.5, no crash)
__global__ void k_sent(float* __restrict__ out) {
    int i = blockIdx.x * 256 + threadIdx.x;
    if (i < NN) out[i] = 0.5f;
}

// ---------------- launch ----------------

extern "C" void kernel_launch(void* const* d_in, const int* in_sizes, int n_in,
                              void* d_out, int out_size, void* d_ws, size_t ws_size,
                              hipStream_t stream) {
    const float* features = (const float*)d_in[0];
    const int* src = (const int*)d_in[1];
    const int* dst = (const int*)d_in[2];
    const float* Wm = (const float*)d_in[4];
    const float* bm = (const float*)d_in[5];
    const float* Wq[3] = {(const float*)d_in[6], (const float*)d_in[12], (const float*)d_in[18]};
    const float* bq[3] = {(const float*)d_in[7], (const float*)d_in[13], (const float*)d_in[19]};
    const float* Wk[3] = {(const float*)d_in[8], (const float*)d_in[14], (const float*)d_in[20]};
    const float* bk[3] = {(const float*)d_in[9], (const float*)d_in[15], (const float*)d_in[21]};
    const float* Wv[3] = {(const float*)d_in[10], (const float*)d_in[16], (const float*)d_in[22]};
    const float* bv[3] = {(const float*)d_in[11], (const float*)d_in[17], (const float*)d_in[23]};
    const float* W1 = (const float*)d_in[24];
    const float* b1 = (const float*)d_in[25];
    const float* W2 = (const float*)d_in[26];
    const float* b2 = (const float*)d_in[27];
    const float* W3 = (const float*)d_in[28];
    const float* b3 = (const float*)d_in[29];
    float* out = (float*)d_out;

    char* ws = (char*)d_ws;
    size_t off = 0;
    auto alloc = [&](size_t b) -> void* {
        void* p = ws + off;
        off = (off + b + 255) & ~(size_t)255;
        return p;
    };

    int* deg_o = (int*)alloc(NN * 4);
    int* deg_i = (int*)alloc(NN * 4);
    int* row_ptr = (int*)alloc((NN + 1) * 4);
    int* cursor = (int*)alloc(NN * 4);
    int* col_src = (int*)alloc((size_t)NE * 4);
    float* ns = (float*)alloc(NN * 4);
    float* nd = (float*)alloc(NN * 4);

    unsigned short* Wmt_h = (unsigned short*)alloc(256 * 256 * 2);
    unsigned short* Wmt_l = (unsigned short*)alloc(256 * 256 * 2);
    unsigned short *Wqkvt_h[3][3], *Wqkvt_l[3][3];
    for (int l = 0; l < 3; ++l)
        for (int m = 0; m < 3; ++m) {
            Wqkvt_h[l][m] = (unsigned short*)alloc(256 * 256 * 2);
            Wqkvt_l[l][m] = (unsigned short*)alloc(256 * 256 * 2);
        }
    unsigned short* W1t_h = (unsigned short*)alloc(512 * 768 * 2);
    unsigned short* W1t_l = (unsigned short*)alloc(512 * 768 * 2);
    unsigned short* W2t_h = (unsigned short*)alloc(256 * 512 * 2);
    unsigned short* W2t_l = (unsigned short*)alloc(256 * 512 * 2);

    float* QKV = (float*)alloc((size_t)NN * 768 * 4);   // also hosts x0, then h1
    float* y = (float*)alloc((size_t)NN * 256 * 4);     // also hosts h2
    float* xcat = (float*)alloc((size_t)NN * 768 * 4);

    float* x0 = QKV;    // dead before QKV first written (after layer-1 prop)
    float* h1 = QKV;    // QKV dead after layer-3 attn; h1 = NN*512 floats <= NN*768
    float* h2 = y;      // y dead after layer-3 V-gemm

    (void)in_sizes; (void)n_in; (void)out_size;

    if (off > ws_size) {  // workspace too small: emit sentinel, don't fault
        k_sent<<<(NN + 255) / 256, 256, 0, stream>>>(out);
        return;
    }

    hipMemsetAsync(deg_o, 0, NN * 4, stream);
    hipMemsetAsync(deg_i, 0, NN * 4, stream);
    k_deg<<<(NE + 255) / 256, 256, 0, stream>>>(src, dst, deg_o, deg_i);
    k_norm<<<(NN + 255) / 256, 256, 0, stream>>>(deg_o, deg_i, ns, nd);
    k_scan<<<1, 1024, 0, stream>>>(deg_i, row_ptr, cursor);
    k_fill<<<(NE + 255) / 256, 256, 0, stream>>>(src, dst, cursor, col_src);

    k_wsplit<<<(256 * 256 + 255) / 256, 256, 0, stream>>>(Wm, Wmt_h, Wmt_l, 256, 256);
    for (int l = 0; l < 3; ++l) {
        k_wsplit<<<(256 * 256 + 255) / 256, 256, 0, stream>>>(Wq[l], Wqkvt_h[l][0], Wqkvt_l[l][0], 256, 256);
        k_wsplit<<<(256 * 256 + 255) / 256, 256, 0, stream>>>(Wk[l], Wqkvt_h[l][1], Wqkvt_l[l][1], 256, 256);
        k_wsplit<<<(256 * 256 + 255) / 256, 256, 0, stream>>>(Wv[l], Wqkvt_h[l][2], Wqkvt_l[l][2], 256, 256);
    }
    k_wsplit<<<(768 * 512 + 255) / 256, 256, 0, stream>>>(W1, W1t_h, W1t_l, 768, 512);
    k_wsplit<<<(512 * 256 + 255) / 256, 256, 0, stream>>>(W2, W2t_h, W2t_l, 512, 256);

    const int MB = (NN + 127) / 128;  // 391
    dim3 gN256(MB, 2), gN512(MB, 4);

    // x0 = relu(features @ Wm + bm)   (x0 lives at QKV base, ld 256)
    k_gemm<<<gN256, 256, 0, stream>>>(features, 256, Wmt_h, Wmt_l, bm,
                                      x0, 256, 0, NN, 256);

    const float* xin = x0;
    int ldx = 256;
    for (int l = 0; l < 3; ++l) {
        k_prop<<<12500, 256, 0, stream>>>(xin, ldx, row_ptr, col_src, ns, nd, y);
        k_gemm<<<gN256, 256, 0, stream>>>(y, 256, Wqkvt_h[l][0], Wqkvt_l[l][0], bq[l],
                                          QKV, 768, 0, NN, 256);
        k_gemm<<<gN256, 256, 0, stream>>>(y, 256, Wqkvt_h[l][1], Wqkvt_l[l][1], bk[l],
                                          QKV, 768, 256, NN, 256);
        k_gemm<<<gN256, 256, 0, stream>>>(y, 256, Wqkvt_h[l][2], Wqkvt_l[l][2], bv[l],
                                          QKV, 768, 512, NN, 256);
        k_attn<<<12500, 256, 0, stream>>>(QKV, row_ptr, col_src, xcat + 256 * l);
        xin = xcat + 256 * l;
        ldx = 768;
    }

    // MLP head
    k_gemm<<<gN512, 256, 0, stream>>>(xcat, 768, W1t_h, W1t_l, b1, h1, 512, 0, NN, 768);
    k_gemm<<<gN256, 256, 0, stream>>>(h1, 512, W2t_h, W2t_l, b2, h2, 256, 0, NN, 512);
    k_final<<<12500, 256, 0, stream>>>(h2, W3, b3, out);
}

// Round 3
// 9.672 us; speedup vs baseline: 1.0254x; 1.0254x over previous
//
#include <hip/hip_runtime.h>
#include <stdint.h>

#define NN 50000
#define NE 800000
#define NBLK 196   // ceil(NN/256)

typedef float f32x4 __attribute__((ext_vector_type(4)));
typedef short s16x8 __attribute__((ext_vector_type(8)));

__device__ __forceinline__ float bf2f(unsigned short u) {
    union { unsigned int i; float f; } v; v.i = ((unsigned int)u) << 16; return v.f;
}
__device__ __forceinline__ unsigned short f2bf(float x) {
    union { float f; unsigned int i; } v; v.f = x;
    unsigned int r = v.i + 0x7FFFu + ((v.i >> 16) & 1u);
    return (unsigned short)(r >> 16);
}

// ---------------- graph preprocessing ----------------

__global__ void k_deg(const int* __restrict__ src, const int* __restrict__ dst,
                      int* __restrict__ dego, int* __restrict__ degi) {
    int e = blockIdx.x * 256 + threadIdx.x;
    if (e < NE) {
        atomicAdd(&dego[src[e]], 1);
        atomicAdd(&degi[dst[e]], 1);
    }
}

__global__ void k_norm(const int* __restrict__ dego, const int* __restrict__ degi,
                       float* __restrict__ ns, float* __restrict__ nd) {
    int i = blockIdx.x * 256 + threadIdx.x;
    if (i < NN) {
        ns[i] = dego[i] > 0 ? rsqrtf((float)dego[i]) : 0.f;
        nd[i] = degi[i] > 0 ? rsqrtf((float)degi[i]) : 0.f;
    }
}

// parallel exclusive scan of deg_i -> row_ptr, cursor (3 phases)
__global__ void k_scanA(const int* __restrict__ deg, int* __restrict__ incl,
                        int* __restrict__ bsum) {
    __shared__ int sm[256];
    int t = threadIdx.x, i = blockIdx.x * 256 + t;
    int v = (i < NN) ? deg[i] : 0;
    sm[t] = v;
    __syncthreads();
#pragma unroll
    for (int off = 1; off < 256; off <<= 1) {
        int tv = (t >= off) ? sm[t - off] : 0;
        __syncthreads();
        sm[t] += tv;
        __syncthreads();
    }
    if (i < NN) incl[i] = sm[t];
    if (t == 255) bsum[blockIdx.x] = sm[255];
}

__global__ void k_scanB(const int* __restrict__ bsum, int* __restrict__ boff,
                        int* __restrict__ row_ptr) {
    __shared__ int sm[256];
    int t = threadIdx.x;
    int v = (t < NBLK) ? bsum[t] : 0;
    sm[t] = v;
    __syncthreads();
#pragma unroll
    for (int off = 1; off < 256; off <<= 1) {
        int tv = (t >= off) ? sm[t - off] : 0;
        __syncthreads();
        sm[t] += tv;
        __syncthreads();
    }
    if (t < NBLK) boff[t] = sm[t] - v;  // exclusive
    if (t == 255) row_ptr[NN] = sm[255];
}

__global__ void k_scanC(const int* __restrict__ deg, const int* __restrict__ incl,
                        const int* __restrict__ boff, int* __restrict__ row_ptr,
                        int* __restrict__ cursor) {
    int i = blockIdx.x * 256 + threadIdx.x;
    if (i < NN) {
        int ex = boff[blockIdx.x] + incl[i] - deg[i];
        row_ptr[i] = ex;
        cursor[i] = ex;
    }
}

__global__ void k_fill(const int* __restrict__ src, const int* __restrict__ dst,
                       int* __restrict__ cursor, int* __restrict__ col_src) {
    int e = blockIdx.x * 256 + threadIdx.x;
    if (e < NE) {
        int slot = atomicAdd(&cursor[dst[e]], 1);
        col_src[slot] = src[e];
    }
}

// ---------------- weight prep ----------------
// W [K,Ncols] fp32 row-major -> Wt hi/lo [Ncols,K] bf16 (B^T layout)
__global__ void k_wsplit(const float* __restrict__ W, unsigned short* __restrict__ hi,
                         unsigned short* __restrict__ lo, int K, int Ncols) {
    int idx = blockIdx.x * 256 + threadIdx.x;
    if (idx < K * Ncols) {
        int n = idx / K, k = idx - n * K;
        float w = W[(size_t)k * Ncols + n];
        unsigned short h = f2bf(w);
        hi[idx] = h;
        lo[idx] = f2bf(w - bf2f(h));
    }
}

struct QkvPtrs {
    const float* w[9];          // [layer*3 + which], each [256,256]
    unsigned short* h[3];       // merged [768][256] per layer
    unsigned short* l[3];
};

__global__ void k_wsplit9(QkvPtrs P) {
    int m = blockIdx.y;               // 0..8
    int layer = m / 3, which = m - layer * 3;
    int idx = blockIdx.x * 256 + threadIdx.x;   // 0..65535
    int n = idx >> 8, k = idx & 255;
    float w = P.w[m][(size_t)k * 256 + n];
    unsigned short h = f2bf(w);
    size_t o = (size_t)(which * 256 + n) * 256 + k;
    P.h[layer][o] = h;
    P.l[layer][o] = f2bf(w - bf2f(h));
}

struct BiasPtrs { const float* b[9]; float* dst; };  // dst [3][768]

__global__ void k_bcat(BiasPtrs P) {
    int m = blockIdx.x;               // 0..8
    int layer = m / 3, which = m - layer * 3;
    int t = threadIdx.x;              // 0..255
    P.dst[layer * 768 + which * 256 + t] = P.b[m][t];
}

// ---------------- GCN propagate: y[d] = nd[d] * sum_{e:dst=d} ns[s] * x[s] ----------------
// One wave per node; lane owns 4 consecutive cols. Next-edge (s, ns) prefetched.

__global__ void k_prop(const float* __restrict__ x, int ldx,
                       const int* __restrict__ row_ptr, const int* __restrict__ col_src,
                       const float* __restrict__ ns, const float* __restrict__ ndv,
                       float* __restrict__ y) {
    int w = (int)((blockIdx.x * 256 + threadIdx.x) >> 6);
    if (w >= NN) return;
    int lane = threadIdx.x & 63;
    int c = lane * 4;
    float a0 = 0, a1 = 0, a2 = 0, a3 = 0;
    int e0 = row_ptr[w], e1 = row_ptr[w + 1];
    int sv = (e0 < e1) ? col_src[e0] : 0;
    float wv = (e0 < e1) ? ns[sv] : 0.f;
    for (int p = e0; p < e1; ++p) {
        int sn = 0; float wn = 0.f;
        if (p + 1 < e1) { sn = col_src[p + 1]; wn = ns[sn]; }
        const float4 xv = *(const float4*)(x + (size_t)sv * ldx + c);
        a0 += wv * xv.x; a1 += wv * xv.y; a2 += wv * xv.z; a3 += wv * xv.w;
        sv = sn; wv = wn;
    }
    float sc = ndv[w];
    float4 o; o.x = a0 * sc; o.y = a1 * sc; o.z = a2 * sc; o.w = a3 * sc;
    *(float4*)(y + (size_t)w * 256 + c) = o;
}

// ---------------- edge attention ----------------
// QKV [NN,768] fp32: cols 0-255 Q, 256-511 K, 512-767 V. One wave per dst node.
// 16-lane group g handles head g; lane covers 4 dims. K+V rows issued together;
// next src index prefetched.

__global__ void k_attn(const float* __restrict__ QKV,
                       const int* __restrict__ row_ptr, const int* __restrict__ col_src,
                       float* __restrict__ xo) {
    int w = (int)((blockIdx.x * 256 + threadIdx.x) >> 6);
    if (w >= NN) return;
    int lane = threadIdx.x & 63;
    int c = lane * 4;
    const float4 q = *(const float4*)(QKV + (size_t)w * 768 + c);
    float v0 = 0, v1 = 0, v2 = 0, v3 = 0, z = 0;
    int e0 = row_ptr[w], e1 = row_ptr[w + 1];
    int sv = (e0 < e1) ? col_src[e0] : 0;
    for (int p = e0; p < e1; ++p) {
        int sn = (p + 1 < e1) ? col_src[p + 1] : 0;
        const float4 kk = *(const float4*)(QKV + (size_t)sv * 768 + 256 + c);
        const float4 vv = *(const float4*)(QKV + (size_t)sv * 768 + 512 + c);
        float t = q.x * kk.x + q.y * kk.y + q.z * kk.z + q.w * kk.w;
        t += __shfl_xor(t, 1);
        t += __shfl_xor(t, 2);
        t += __shfl_xor(t, 4);
        t += __shfl_xor(t, 8);
        float scv = __expf(fminf(fmaxf(t * 0.125f, -10.f), 10.f));
        v0 += scv * vv.x; v1 += scv * vv.y; v2 += scv * vv.z; v3 += scv * vv.w;
        z += scv;
        sv = sn;
    }
    float inv = 1.f / (z + 1e-6f);
    float4 o; o.x = v0 * inv; o.y = v1 * inv; o.z = v2 * inv; o.w = v3 * inv;
    *(float4*)(xo + (size_t)w * 768 + c) = o;
}

// ---------------- split-bf16 GEMM: C = relu(A @ W + b) ----------------
// A: fp32 [M,K] (lda), split to hi/lo bf16 in registers during LDS staging.
// B: hi/lo bf16 B^T [Ncols,K]. 3-term MFMA (hh + hl + lh) ~ fp32 accuracy.
// 128x128 tile, BK=32, 4 waves (2x2 of 64x64), mfma_f32_16x16x32_bf16.

__global__ __launch_bounds__(256) void k_gemm(
    const float* __restrict__ A, int lda,
    const unsigned short* __restrict__ Bhi, const unsigned short* __restrict__ Blo,
    const float* __restrict__ bias,
    float* __restrict__ C, int ldc, int coff, int M, int K) {
    __shared__ unsigned short sA[2][128][40];
    __shared__ unsigned short sB[2][128][40];
    const int tid = threadIdx.x;
    const int lane = tid & 63;
    const int wid = tid >> 6;
    const int wm = wid & 1, wn = wid >> 1;
    const int fr = lane & 15, kg = lane >> 4;
    const int brow = blockIdx.x * 128;
    const int bcol = blockIdx.y * 128;
    f32x4 acc[4][4] = {};

    for (int k0 = 0; k0 < K; k0 += 32) {
#pragma unroll
        for (int rep = 0; rep < 2; ++rep) {
            int s = tid + rep * 256;
            int row = s >> 2, ks = (s & 3) * 8;
            int gr = brow + row;
            float4 f0 = make_float4(0, 0, 0, 0), f1 = make_float4(0, 0, 0, 0);
            if (gr < M) {
                const float4* ap = (const float4*)(A + (size_t)gr * lda + k0 + ks);
                f0 = ap[0];
                f1 = ap[1];
            }
            ushort4 h0, h1v, l0, l1v;
            h0.x = f2bf(f0.x); l0.x = f2bf(f0.x - bf2f(h0.x));
            h0.y = f2bf(f0.y); l0.y = f2bf(f0.y - bf2f(h0.y));
            h0.z = f2bf(f0.z); l0.z = f2bf(f0.z - bf2f(h0.z));
            h0.w = f2bf(f0.w); l0.w = f2bf(f0.w - bf2f(h0.w));
            h1v.x = f2bf(f1.x); l1v.x = f2bf(f1.x - bf2f(h1v.x));
            h1v.y = f2bf(f1.y); l1v.y = f2bf(f1.y - bf2f(h1v.y));
            h1v.z = f2bf(f1.z); l1v.z = f2bf(f1.z - bf2f(h1v.z));
            h1v.w = f2bf(f1.w); l1v.w = f2bf(f1.w - bf2f(h1v.w));
            *(ushort4*)&sA[0][row][ks] = h0;
            *(ushort4*)&sA[0][row][ks + 4] = h1v;
            *(ushort4*)&sA[1][row][ks] = l0;
            *(ushort4*)&sA[1][row][ks + 4] = l1v;
            size_t bbase = (size_t)(bcol + row) * K + k0 + ks;
            *(uint4*)&sB[0][row][ks] = *(const uint4*)(Bhi + bbase);
            *(uint4*)&sB[1][row][ks] = *(const uint4*)(Blo + bbase);
        }
        __syncthreads();
        s16x8 ah[4], al[4], bh[4], bl[4];
#pragma unroll
        for (int f = 0; f < 4; ++f) {
            ah[f] = *(const s16x8*)&sA[0][wm * 64 + f * 16 + fr][kg * 8];
            al[f] = *(const s16x8*)&sA[1][wm * 64 + f * 16 + fr][kg * 8];
            bh[f] = *(const s16x8*)&sB[0][wn * 64 + f * 16 + fr][kg * 8];
            bl[f] = *(const s16x8*)&sB[1][wn * 64 + f * 16 + fr][kg * 8];
        }
#pragma unroll
        for (int i = 0; i < 4; ++i)
#pragma unroll
            for (int j = 0; j < 4; ++j) {
                acc[i][j] = __builtin_amdgcn_mfma_f32_16x16x32_bf16(ah[i], bh[j], acc[i][j], 0, 0, 0);
                acc[i][j] = __builtin_amdgcn_mfma_f32_16x16x32_bf16(ah[i], bl[j], acc[i][j], 0, 0, 0);
                acc[i][j] = __builtin_amdgcn_mfma_f32_16x16x32_bf16(al[i], bh[j], acc[i][j], 0, 0, 0);
            }
        __syncthreads();
    }

#pragma unroll
    for (int i = 0; i < 4; ++i) {
#pragma unroll
        for (int j = 0; j < 4; ++j) {
            int colL = bcol + wn * 64 + j * 16 + fr;
            float bb = bias[colL];
#pragma unroll
            for (int r = 0; r < 4; ++r) {
                int row = brow + wm * 64 + i * 16 + kg * 4 + r;
                if (row < M) {
                    C[(size_t)row * ldc + coff + colL] = fmaxf(acc[i][j][r] + bb, 0.f);
                }
            }
        }
    }
}

// ---------------- final row-dot + sigmoid ----------------

__global__ void k_final(const float* __restrict__ h2, const float* __restrict__ W3,
                        const float* __restrict__ b3, float* __restrict__ out) {
    int w = (int)((blockIdx.x * 256 + threadIdx.x) >> 6);
    if (w >= NN) return;
    int lane = threadIdx.x & 63;
    float4 h = *(const float4*)(h2 + (size_t)w * 256 + lane * 4);
    float4 ww = *(const float4*)(W3 + lane * 4);
    float p = h.x * ww.x + h.y * ww.y + h.z * ww.z + h.w * ww.w;
    p += __shfl_xor(p, 1);
    p += __shfl_xor(p, 2);
    p += __shfl_xor(p, 4);
    p += __shfl_xor(p, 8);
    p += __shfl_xor(p, 16);
    p += __shfl_xor(p, 32);
    if (lane == 0) out[w] = 1.f / (1.f + __expf(-(p + b3[0])));
}

// sentinel: written iff ws_size is too small (diagnosable absmax ~= 0.5, no crash)
__global__ void k_sent(float* __restrict__ out) {
    int i = blockIdx.x * 256 + threadIdx.x;
    if (i < NN) out[i] = 0.5f;
}

// ---------------- launch ----------------

extern "C" void kernel_launch(void* const* d_in, const int* in_sizes, int n_in,
                              void* d_out, int out_size, void* d_ws, size_t ws_size,
                              hipStream_t stream) {
    const float* features = (const float*)d_in[0];
    const int* src = (const int*)d_in[1];
    const int* dst = (const int*)d_in[2];
    const float* Wm = (const float*)d_in[4];
    const float* bm = (const float*)d_in[5];
    const float* W1 = (const float*)d_in[24];
    const float* b1 = (const float*)d_in[25];
    const float* W2 = (const float*)d_in[26];
    const float* b2 = (const float*)d_in[27];
    const float* W3 = (const float*)d_in[28];
    const float* b3 = (const float*)d_in[29];
    float* out = (float*)d_out;

    char* ws = (char*)d_ws;
    size_t off = 0;
    auto alloc = [&](size_t b) -> void* {
        void* p = ws + off;
        off = (off + b + 255) & ~(size_t)255;
        return p;
    };

    int* deg_o = (int*)alloc(NN * 4);
    int* deg_i = (int*)alloc(NN * 4);
    int* row_ptr = (int*)alloc((NN + 1) * 4);
    int* cursor = (int*)alloc(NN * 4);
    int* col_src = (int*)alloc((size_t)NE * 4);
    float* ns = (float*)alloc(NN * 4);
    float* nd = (float*)alloc(NN * 4);
    int* incl = (int*)alloc(NN * 4);
    int* bsum = (int*)alloc(NBLK * 4);
    int* boff = (int*)alloc(NBLK * 4);

    unsigned short* Wmt_h = (unsigned short*)alloc(256 * 256 * 2);
    unsigned short* Wmt_l = (unsigned short*)alloc(256 * 256 * 2);
    unsigned short *Wqkvt_h[3], *Wqkvt_l[3];
    for (int l = 0; l < 3; ++l) {
        Wqkvt_h[l] = (unsigned short*)alloc(768 * 256 * 2);
        Wqkvt_l[l] = (unsigned short*)alloc(768 * 256 * 2);
    }
    float* bqkv = (float*)alloc(3 * 768 * 4);
    unsigned short* W1t_h = (unsigned short*)alloc(512 * 768 * 2);
    unsigned short* W1t_l = (unsigned short*)alloc(512 * 768 * 2);
    unsigned short* W2t_h = (unsigned short*)alloc(256 * 512 * 2);
    unsigned short* W2t_l = (unsigned short*)alloc(256 * 512 * 2);

    float* QKV = (float*)alloc((size_t)NN * 768 * 4);   // also hosts x0, then h1
    float* y = (float*)alloc((size_t)NN * 256 * 4);     // also hosts h2
    float* xcat = (float*)alloc((size_t)NN * 768 * 4);

    float* x0 = QKV;    // dead before QKV first written
    float* h1 = QKV;    // QKV dead after layer-3 attn
    float* h2 = y;      // y dead after layer-3 QKV gemm

    (void)in_sizes; (void)n_in; (void)out_size;

    if (off > ws_size) {
        k_sent<<<(NN + 255) / 256, 256, 0, stream>>>(out);
        return;
    }

    hipMemsetAsync(deg_o, 0, NN * 4, stream);
    hipMemsetAsync(deg_i, 0, NN * 4, stream);
    k_deg<<<(NE + 255) / 256, 256, 0, stream>>>(src, dst, deg_o, deg_i);
    k_norm<<<NBLK, 256, 0, stream>>>(deg_o, deg_i, ns, nd);
    k_scanA<<<NBLK, 256, 0, stream>>>(deg_i, incl, bsum);
    k_scanB<<<1, 256, 0, stream>>>(bsum, boff, row_ptr);
    k_scanC<<<NBLK, 256, 0, stream>>>(deg_i, incl, boff, row_ptr, cursor);
    k_fill<<<(NE + 255) / 256, 256, 0, stream>>>(src, dst, cursor, col_src);

    k_wsplit<<<(256 * 256 + 255) / 256, 256, 0, stream>>>(Wm, Wmt_h, Wmt_l, 256, 256);
    QkvPtrs qp;
    BiasPtrs bp;
    for (int l = 0; l < 3; ++l) {
        for (int m = 0; m < 3; ++m) {
            qp.w[l * 3 + m] = (const float*)d_in[6 + l * 6 + m * 2];
            bp.b[l * 3 + m] = (const float*)d_in[7 + l * 6 + m * 2];
        }
        qp.h[l] = Wqkvt_h[l];
        qp.l[l] = Wqkvt_l[l];
    }
    bp.dst = bqkv;
    k_wsplit9<<<dim3(256, 9), 256, 0, stream>>>(qp);
    k_bcat<<<9, 256, 0, stream>>>(bp);
    k_wsplit<<<(768 * 512 + 255) / 256, 256, 0, stream>>>(W1, W1t_h, W1t_l, 768, 512);
    k_wsplit<<<(512 * 256 + 255) / 256, 256, 0, stream>>>(W2, W2t_h, W2t_l, 512, 256);

    const int MB = (NN + 127) / 128;  // 391
    dim3 gN256(MB, 2), gN512(MB, 4), gN768(MB, 6);

    // x0 = relu(features @ Wm + bm)   (x0 lives at QKV base, ld 256)
    k_gemm<<<gN256, 256, 0, stream>>>(features, 256, Wmt_h, Wmt_l, bm,
                                      x0, 256, 0, NN, 256);

    const float* xin = x0;
    int ldx = 256;
    for (int l = 0; l < 3; ++l) {
        k_prop<<<12500, 256, 0, stream>>>(xin, ldx, row_ptr, col_src, ns, nd, y);
        k_gemm<<<gN768, 256, 0, stream>>>(y, 256, Wqkvt_h[l], Wqkvt_l[l], bqkv + l * 768,
                                          QKV, 768, 0, NN, 256);
        k_attn<<<12500, 256, 0, stream>>>(QKV, row_ptr, col_src, xcat + 256 * l);
        xin = xcat + 256 * l;
        ldx = 768;
    }

    // MLP head
    k_gemm<<<gN512, 256, 0, stream>>>(xcat, 768, W1t_h, W1t_l, b1, h1, 512, 0, NN, 768);
    k_gemm<<<gN256, 256, 0, stream>>>(h1, 512, W2t_h, W2t_l, b2, h2, 256, 0, NN, 512);
    k_final<<<12500, 256, 0, stream>>>(h2, W3, b3, out);
}